// Round 8
// baseline (738.040 us; speedup 1.0000x reference)
//
#include <hip/hip_runtime.h>

// CapsuleMappingTiny on MFMA, v3: v2 + spill fix.
// v2 post-mortem: __launch_bounds__(256,2) let the allocator shrink to 128
// VGPRs and spill the register-resident K fragments -> ~660MB/launch scratch
// traffic (FETCH 783MB, WRITE 195MB). Fix: amdgpu_waves_per_eu(2,2) pins
// exact occupancy (LDS caps at 2 blocks/CU anyway) so the full 256-VGPR
// budget is used, + two-pass K prologue to cut transient pressure.

typedef __attribute__((ext_vector_type(8))) short bf16x8;
typedef __attribute__((ext_vector_type(4))) float f32x4;
typedef __attribute__((ext_vector_type(4))) unsigned short u16x4;
typedef unsigned short u16;

#define MFMA(a, b, c) __builtin_amdgcn_mfma_f32_16x16x32_bf16((a), (b), (c), 0, 0, 0)

__device__ __forceinline__ u16 f2bf(float x) {
    union { float f; unsigned u; } v; v.f = x;
    unsigned r = v.u + 0x7fffu + ((v.u >> 16) & 1u);
    return (u16)(r >> 16);
}
__device__ __forceinline__ float bf2f(u16 h) {
    union { unsigned u; float f; } v; v.u = ((unsigned)h) << 16;
    return v.f;
}
// swizzled ushort index; c8 = 8-elem group, c0 = within-group
__device__ __forceinline__ int ix256(int r, int c8, int c0) {
    return r * 256 + (((c8) ^ (r & 7)) << 3) + c0;
}
__device__ __forceinline__ int ix64(int r, int c8, int c0) {
    return r * 64 + (((c8) ^ (r & 7)) << 3) + c0;
}

__global__
__attribute__((amdgpu_flat_work_group_size(256, 256)))
__attribute__((amdgpu_waves_per_eu(2, 2)))
void capsule_mfma3_kernel(const float* __restrict__ kin,
                          const float* __restrict__ qin,
                          const float* __restrict__ vin,
                          const float* __restrict__ g1,
                          const float* __restrict__ b1,
                          const float* __restrict__ g2,
                          const float* __restrict__ b2,
                          float* __restrict__ out)
{
    // 77,312 B total LDS -> 2 blocks/CU
    __shared__ __align__(16) u16 qh[64 * 256];   // 32 KB  qn hi / wT hi [256][64]
    __shared__ __align__(16) u16 ql[64 * 256];   // 32 KB  qn lo / wT lo
    __shared__ __align__(16) u16 mh[64 * 64];    // 8 KB   m hi  / epilogue redA (float)
    __shared__ float g1s[64], b1s[64];
    __shared__ float c1f[256], c2f[256];
    __shared__ float muA[64], invA[64], mu2[64], inv2[64];

    const int tid = threadIdx.x;
    const int wid = tid >> 6;         // wave 0..3
    const int l   = tid & 63;         // lane
    const int g   = l >> 4;           // quarter-wave 0..3
    const int l15 = l & 15;
    const int b   = blockIdx.x >> 4;
    const int kt  = blockIdx.x & 15;

    const float* kb = kin + (size_t)(b * 1024 + kt * 64) * 256;
    const float* qb = qin + (size_t)b * 1024 * 256;
    const float* vb = vin + (size_t)b * 1024 * 256;

    // ---- prologue: K-tile A-fragments into registers (two-pass, low peak) ----
    // Lane (g,l15) of wave wid needs kn row (wid*16+l15), cols [(kk*4+g)*8, +8).
    bf16x8 kfh[8], kfl[8];
    {
        const float* krp = kb + (wid * 16 + l15) * 256;
        // pass 1: sum of squares of this lane's 64 elements; combine quarters
        float ssq = 0.f;
        #pragma unroll
        for (int kk = 0; kk < 8; ++kk) {
            const float4 a = *(const float4*)(krp + (kk * 4 + g) * 8);
            const float4 c = *(const float4*)(krp + (kk * 4 + g) * 8 + 4);
            ssq += a.x * a.x + a.y * a.y + a.z * a.z + a.w * a.w +
                   c.x * c.x + c.y * c.y + c.z * c.z + c.w * c.w;
        }
        ssq += __shfl_xor(ssq, 16);
        ssq += __shfl_xor(ssq, 32);
        const float sc = rsqrtf(fmaxf(ssq, 1e-12f));
        // pass 2: reload (L1/L2-hot), scale, split to bf16 hi/lo
        #pragma unroll
        for (int kk = 0; kk < 8; ++kk) {
            const float4 a = *(const float4*)(krp + (kk * 4 + g) * 8);
            const float4 c = *(const float4*)(krp + (kk * 4 + g) * 8 + 4);
            const float p[8] = {sc * a.x, sc * a.y, sc * a.z, sc * a.w,
                                sc * c.x, sc * c.y, sc * c.z, sc * c.w};
            union { bf16x8 v; u16 s[8]; } uh, ul;
            #pragma unroll
            for (int j = 0; j < 8; ++j) {
                const u16 h = f2bf(p[j]);
                uh.s[j] = h;
                ul.s[j] = f2bf(p[j] - bf2f(h));
            }
            kfh[kk] = uh.v;
            kfl[kk] = ul.v;
        }
    }

    // persistent state
    f32x4 acc[4][4];                  // out^T frags [fi d][fk k]
    #pragma unroll
    for (int i = 0; i < 4; ++i)
        #pragma unroll
        for (int j = 0; j < 4; ++j) acc[i][j] = (f32x4){0.f, 0.f, 0.f, 0.f};
    float rsp[4]  = {0.f, 0.f, 0.f, 0.f};   // LN1 raw row-sum partials (per reg e)
    float rssp[4] = {0.f, 0.f, 0.f, 0.f};
    float c1p[4]  = {0.f, 0.f, 0.f, 0.f};   // per-lane d = d0*64 + l
    float c2p[4]  = {0.f, 0.f, 0.f, 0.f};

    #pragma unroll 1
    for (int qt = 0; qt < 16; ++qt) {
        const int qoff = qt * 64;
        __syncthreads();   // prior GEMM2 done reading wT (qh/ql)

        // ---- stage+normalize+split q tile into qh/ql ----
        #pragma unroll
        for (int i = 0; i < 16; ++i) {
            const int r = i * 4 + wid;
            float4 x = *(const float4*)(qb + (size_t)(qoff + r) * 256 + l * 4);
            float ssq = x.x * x.x + x.y * x.y + x.z * x.z + x.w * x.w;
            #pragma unroll
            for (int s = 1; s < 64; s <<= 1) ssq += __shfl_xor(ssq, s);
            const float sc = rsqrtf(fmaxf(ssq, 1e-12f));
            x.x *= sc; x.y *= sc; x.z *= sc; x.w *= sc;
            u16 h0 = f2bf(x.x), h1 = f2bf(x.y), h2 = f2bf(x.z), h3 = f2bf(x.w);
            u16x4 hh = {h0, h1, h2, h3};
            u16x4 ll = {f2bf(x.x - bf2f(h0)), f2bf(x.y - bf2f(h1)),
                        f2bf(x.z - bf2f(h2)), f2bf(x.w - bf2f(h3))};
            const int idx = ix256(r, l >> 1, (l & 1) * 4);
            *(u16x4*)(qh + idx) = hh;
            *(u16x4*)(ql + idx) = ll;
        }
        if (tid < 64) { g1s[tid] = g1[qoff + tid]; b1s[tid] = b1[qoff + tid]; }
        __syncthreads();   // qh/ql, g1s/b1s visible

        // ---- GEMM1: m[16w + g*4+e][fj*16 + l15], A from registers ----
        f32x4 macc[4];
        #pragma unroll
        for (int fj = 0; fj < 4; ++fj) macc[fj] = (f32x4){0.f, 0.f, 0.f, 0.f};
        #pragma unroll
        for (int kk = 0; kk < 8; ++kk) {
            const int c8 = kk * 4 + g;
            #pragma unroll
            for (int fj = 0; fj < 4; ++fj) {
                const int brow = fj * 16 + l15;
                const bf16x8 bh = *(const bf16x8*)(qh + ix256(brow, c8, 0));
                const bf16x8 bl = *(const bf16x8*)(ql + ix256(brow, c8, 0));
                macc[fj] = MFMA(kfh[kk], bh, macc[fj]);
                macc[fj] = MFMA(kfh[kk], bl, macc[fj]);
                macc[fj] = MFMA(kfl[kk], bh, macc[fj]);
            }
        }
        // LN1 raw stats + m -> bf16 hi into mh
        #pragma unroll
        for (int fj = 0; fj < 4; ++fj) {
            #pragma unroll
            for (int e = 0; e < 4; ++e) {
                const float v = macc[fj][e];
                rsp[e] += v; rssp[e] += v * v;
                const int row = wid * 16 + g * 4 + e;
                const int q = fj * 16 + l15;
                mh[ix64(row, (q >> 3), q & 7)] = f2bf(v);
            }
        }
        __syncthreads();   // mh visible; all waves done reading qh/ql

        // ---- stage w = g1*v transposed: wT[d][q] into qh/ql ----
        #pragma unroll
        for (int q0 = 0; q0 < 4; ++q0) {
            const int qq = wid * 16 + q0 * 4;   // 4-aligned q within tile
            const float g1v0 = g1s[qq], g1v1 = g1s[qq + 1];
            const float g1v2 = g1s[qq + 2], g1v3 = g1s[qq + 3];
            const float b1v0 = b1s[qq], b1v1 = b1s[qq + 1];
            const float b1v2 = b1s[qq + 2], b1v3 = b1s[qq + 3];
            #pragma unroll
            for (int d0 = 0; d0 < 4; ++d0) {
                const int d = d0 * 64 + l;
                const float x0 = vb[(size_t)(qoff + qq + 0) * 256 + d];
                const float x1 = vb[(size_t)(qoff + qq + 1) * 256 + d];
                const float x2 = vb[(size_t)(qoff + qq + 2) * 256 + d];
                const float x3 = vb[(size_t)(qoff + qq + 3) * 256 + d];
                const float w0 = g1v0 * x0, w1 = g1v1 * x1, w2 = g1v2 * x2, w3 = g1v3 * x3;
                c1p[d0] += w0 + w1 + w2 + w3;
                c2p[d0] += b1v0 * x0 + b1v1 * x1 + b1v2 * x2 + b1v3 * x3;
                u16 h0 = f2bf(w0), h1 = f2bf(w1), h2 = f2bf(w2), h3 = f2bf(w3);
                u16x4 hh = {h0, h1, h2, h3};
                u16x4 ll = {f2bf(w0 - bf2f(h0)), f2bf(w1 - bf2f(h1)),
                            f2bf(w2 - bf2f(h2)), f2bf(w3 - bf2f(h3))};
                const int idx = ix64(d, qq >> 3, qq & 7);   // 4-run within 8-group
                *(u16x4*)(qh + idx) = hh;
                *(u16x4*)(ql + idx) = ll;
            }
        }
        __syncthreads();   // wT visible

        // ---- GEMM2: out^T[64w+fi*16+g*4+e][fk*16+l15] += wT x m (2-pass) ----
        #pragma unroll
        for (int kk2 = 0; kk2 < 2; ++kk2) {
            const int c8 = kk2 * 4 + g;
            bf16x8 awh[4], awl[4], bm[4];
            #pragma unroll
            for (int fi = 0; fi < 4; ++fi) {
                const int drow = wid * 64 + fi * 16 + l15;
                awh[fi] = *(const bf16x8*)(qh + ix64(drow, c8, 0));
                awl[fi] = *(const bf16x8*)(ql + ix64(drow, c8, 0));
            }
            #pragma unroll
            for (int fk = 0; fk < 4; ++fk) {
                const int krow = fk * 16 + l15;
                bm[fk] = *(const bf16x8*)(mh + ix64(krow, c8, 0));
            }
            #pragma unroll
            for (int fi = 0; fi < 4; ++fi)
                #pragma unroll
                for (int fk = 0; fk < 4; ++fk) {
                    acc[fi][fk] = MFMA(awh[fi], bm[fk], acc[fi][fk]);
                    acc[fi][fk] = MFMA(awl[fi], bm[fk], acc[fi][fk]);
                }
        }
    }

    // ================= epilogue =================
    __syncthreads();   // last GEMM2 reads done -> reuse mh, qh as float scratch
    float* redA = (float*)mh;   // 2048 floats available
    float* redB = (float*)qh;

    #pragma unroll
    for (int d0 = 0; d0 < 4; ++d0) {
        redA[wid * 256 + d0 * 64 + l] = c1p[d0];
        redB[wid * 256 + d0 * 64 + l] = c2p[d0];
    }
    // LN1 stats: reduce rsp/rssp over l15 (q-direction)
    #pragma unroll
    for (int e = 0; e < 4; ++e) {
        float s = rsp[e], ss = rssp[e];
        s += __shfl_xor(s, 1);  ss += __shfl_xor(ss, 1);
        s += __shfl_xor(s, 2);  ss += __shfl_xor(ss, 2);
        s += __shfl_xor(s, 4);  ss += __shfl_xor(ss, 4);
        s += __shfl_xor(s, 8);  ss += __shfl_xor(ss, 8);
        if (l15 == 0) {
            const int k = wid * 16 + g * 4 + e;
            const float mu = s * (1.f / 1024.f);
            const float var = ss * (1.f / 1024.f) - mu * mu;
            muA[k] = mu;
            invA[k] = rsqrtf(var + 1e-3f);
        }
    }
    __syncthreads();
    {
        const float c1s = redA[tid] + redA[256 + tid] + redA[512 + tid] + redA[768 + tid];
        const float c2s = redB[tid] + redB[256 + tid] + redB[512 + tid] + redB[768 + tid];
        c1f[tid] = c1s;
        c2f[tid] = c2s;
    }
    __syncthreads();

    // LN1-fixup in registers + LN2 partial stats
    float s2p[4] = {0.f, 0.f, 0.f, 0.f}, ss2p[4] = {0.f, 0.f, 0.f, 0.f};
    #pragma unroll
    for (int fi = 0; fi < 4; ++fi) {
        const int dbase = wid * 64 + fi * 16 + g * 4;
        const float4 c1v = *(const float4*)(c1f + dbase);
        const float4 c2v = *(const float4*)(c2f + dbase);
        #pragma unroll
        for (int fk = 0; fk < 4; ++fk) {
            const int k = fk * 16 + l15;
            const float mu = muA[k], inv = invA[k];
            float pre;
            pre = inv * (acc[fi][fk][0] - mu * c1v.x) + c2v.x; acc[fi][fk][0] = pre;
            s2p[fk] += pre; ss2p[fk] += pre * pre;
            pre = inv * (acc[fi][fk][1] - mu * c1v.y) + c2v.y; acc[fi][fk][1] = pre;
            s2p[fk] += pre; ss2p[fk] += pre * pre;
            pre = inv * (acc[fi][fk][2] - mu * c1v.z) + c2v.z; acc[fi][fk][2] = pre;
            s2p[fk] += pre; ss2p[fk] += pre * pre;
            pre = inv * (acc[fi][fk][3] - mu * c1v.w) + c2v.w; acc[fi][fk][3] = pre;
            s2p[fk] += pre; ss2p[fk] += pre * pre;
        }
    }
    __syncthreads();   // redA/redB free for LN2 reuse
    #pragma unroll
    for (int fk = 0; fk < 4; ++fk) {
        float s = s2p[fk], ss = ss2p[fk];
        s += __shfl_xor(s, 16); ss += __shfl_xor(ss, 16);
        s += __shfl_xor(s, 32); ss += __shfl_xor(ss, 32);
        if (g == 0) {   // l < 16
            redA[wid * 64 + fk * 16 + l15] = s;
            redB[wid * 64 + fk * 16 + l15] = ss;
        }
    }
    __syncthreads();
    if (tid < 64) {
        const float s  = redA[tid] + redA[64 + tid] + redA[128 + tid] + redA[192 + tid];
        const float ss = redB[tid] + redB[64 + tid] + redB[128 + tid] + redB[192 + tid];
        const float mu = s * (1.f / 256.f);
        const float var = ss * (1.f / 256.f) - mu * mu;
        mu2[tid] = mu;
        inv2[tid] = rsqrtf(var + 1e-3f);
    }
    __syncthreads();

    // final LN2 apply + store (out^T frags -> row-major out)
    #pragma unroll
    for (int fi = 0; fi < 4; ++fi) {
        const int dbase = wid * 64 + fi * 16 + g * 4;
        const float4 gv = *(const float4*)(g2 + dbase);
        const float4 bv = *(const float4*)(b2 + dbase);
        #pragma unroll
        for (int fk = 0; fk < 4; ++fk) {
            const int k = fk * 16 + l15;
            const float mu = mu2[k], inv = inv2[k];
            float4 o;
            o.x = (acc[fi][fk][0] - mu) * inv * gv.x + bv.x;
            o.y = (acc[fi][fk][1] - mu) * inv * gv.y + bv.y;
            o.z = (acc[fi][fk][2] - mu) * inv * gv.z + bv.z;
            o.w = (acc[fi][fk][3] - mu) * inv * gv.w + bv.w;
            *(float4*)(out + (size_t)(b * 1024 + kt * 64 + k) * 256 + dbase) = o;
        }
    }
}

extern "C" void kernel_launch(void* const* d_in, const int* in_sizes, int n_in,
                              void* d_out, int out_size, void* d_ws, size_t ws_size,
                              hipStream_t stream) {
    const float* kin = (const float*)d_in[0];
    const float* qin = (const float*)d_in[1];
    const float* vin = (const float*)d_in[2];
    const float* g1  = (const float*)d_in[3];
    const float* b1  = (const float*)d_in[4];
    const float* g2  = (const float*)d_in[5];
    const float* b2  = (const float*)d_in[6];
    float* out = (float*)d_out;

    hipLaunchKernelGGL(capsule_mfma3_kernel, dim3(512), dim3(256), 0, stream,
                       kin, qin, vin, g1, b1, g2, b2, out);
}

// Round 9
// 670.226 us; speedup vs baseline: 1.1012x; 1.1012x over previous
//
#include <hip/hip_runtime.h>

// CapsuleMappingTiny on MFMA, v4: fit-the-budget redesign.
// v2/v3 post-mortem: allocator pins 128 VGPRs (occupancy attrs ineffective);
// persistent register K-fragments (64 VGPR) spilled -> 660MB/launch scratch.
// v4: NO persistent register tiles. K hi-only in LDS (32KB), q hi-only,
// GEMM1 = Kh*Qh (1 pass), GEMM2 = wTh*mh (1 pass). Arch pressure <=~124
// everywhere -> no spill at budget 128. LDS 72.3KB -> 2 blocks/CU, 512
// blocks in one round. XCD swizzle co-locates each batch's 16 blocks.
// Error budget: dropped cross terms ~1e-4 on m (scale 0.0625) + 1e-3 final
// from w-hi -> absmax ~0.031->0.035 (v2's 0.03125 passed).

typedef __attribute__((ext_vector_type(8))) short bf16x8;
typedef __attribute__((ext_vector_type(4))) float f32x4;
typedef __attribute__((ext_vector_type(4))) unsigned short u16x4;
typedef unsigned short u16;

#define MFMA(a, b, c) __builtin_amdgcn_mfma_f32_16x16x32_bf16((a), (b), (c), 0, 0, 0)

__device__ __forceinline__ u16 f2bf(float x) {
    union { float f; unsigned u; } v; v.f = x;
    unsigned r = v.u + 0x7fffu + ((v.u >> 16) & 1u);
    return (u16)(r >> 16);
}
// swizzled ushort index; c8 = 16B chunk index, c0 = ushort within chunk
__device__ __forceinline__ int ix256(int r, int c8, int c0) {
    return r * 256 + (((c8) ^ (r & 7)) << 3) + c0;
}
__device__ __forceinline__ int ix64(int r, int c8, int c0) {
    return r * 64 + (((c8) ^ (r & 7)) << 3) + c0;
}

__global__ __launch_bounds__(256)
void capsule_mfma4_kernel(const float* __restrict__ kin,
                          const float* __restrict__ qin,
                          const float* __restrict__ vin,
                          const float* __restrict__ g1,
                          const float* __restrict__ b1,
                          const float* __restrict__ g2,
                          const float* __restrict__ b2,
                          float* __restrict__ out)
{
    // 74,240 B total -> 2 blocks/CU
    __shared__ __align__(16) u16 kh[64 * 256];   // 32 KB  kn hi (persistent)
    __shared__ __align__(16) u16 qh[64 * 256];   // 32 KB  qn hi / wT hi [256][64]
    __shared__ __align__(16) u16 mh[64 * 64];    // 8 KB   m hi / epilogue redA (float)
    __shared__ float g1s[64], b1s[64];
    __shared__ float c1f[256], c2f[256];
    __shared__ float muA[64], invA[64], mu2[64], inv2[64];

    const int tid = threadIdx.x;
    const int wid = tid >> 6;         // wave 0..3
    const int l   = tid & 63;         // lane
    const int g   = l >> 4;           // quarter-wave 0..3
    const int l15 = l & 15;
    // XCD swizzle: dispatch d -> XCD d%8; keep each XCD on 4 contiguous batches
    const int lb  = ((blockIdx.x & 7) << 6) | (blockIdx.x >> 3);
    const int b   = lb >> 4;
    const int kt  = lb & 15;

    const float* kb = kin + (size_t)(b * 1024 + kt * 64) * 256;
    const float* qb = qin + (size_t)b * 1024 * 256;
    const float* vb = vin + (size_t)b * 1024 * 256;

    // ---- prologue: stage + normalize K tile, bf16-hi, into LDS ----
    #pragma unroll
    for (int i = 0; i < 16; ++i) {
        const int r = i * 4 + wid;
        float4 x = *(const float4*)(kb + r * 256 + l * 4);
        float ssq = x.x * x.x + x.y * x.y + x.z * x.z + x.w * x.w;
        #pragma unroll
        for (int s = 1; s < 64; s <<= 1) ssq += __shfl_xor(ssq, s);
        const float sc = rsqrtf(fmaxf(ssq, 1e-12f));
        u16x4 hh = {f2bf(sc * x.x), f2bf(sc * x.y), f2bf(sc * x.z), f2bf(sc * x.w)};
        *(u16x4*)(kh + ix256(r, l >> 1, (l & 1) * 4)) = hh;
    }

    // persistent state
    f32x4 acc[4][4];                  // out^T frags [fi d][fk k]
    #pragma unroll
    for (int i = 0; i < 4; ++i)
        #pragma unroll
        for (int j = 0; j < 4; ++j) acc[i][j] = (f32x4){0.f, 0.f, 0.f, 0.f};
    float rsp[4]  = {0.f, 0.f, 0.f, 0.f};   // LN1 raw row-sum partials (per reg e)
    float rssp[4] = {0.f, 0.f, 0.f, 0.f};
    float c1p[4]  = {0.f, 0.f, 0.f, 0.f};   // per-lane d = d0*64 + l
    float c2p[4]  = {0.f, 0.f, 0.f, 0.f};

    #pragma unroll 1
    for (int qt = 0; qt < 16; ++qt) {
        const int qoff = qt * 64;
        __syncthreads();   // prior GEMM2 done reading wT (qh); (t=0: K staged)

        // ---- stage + normalize q tile, bf16-hi ----
        #pragma unroll
        for (int i = 0; i < 16; ++i) {
            const int r = i * 4 + wid;
            float4 x = *(const float4*)(qb + (size_t)(qoff + r) * 256 + l * 4);
            float ssq = x.x * x.x + x.y * x.y + x.z * x.z + x.w * x.w;
            #pragma unroll
            for (int s = 1; s < 64; s <<= 1) ssq += __shfl_xor(ssq, s);
            const float sc = rsqrtf(fmaxf(ssq, 1e-12f));
            u16x4 hh = {f2bf(sc * x.x), f2bf(sc * x.y), f2bf(sc * x.z), f2bf(sc * x.w)};
            *(u16x4*)(qh + ix256(r, l >> 1, (l & 1) * 4)) = hh;
        }
        if (tid < 64) { g1s[tid] = g1[qoff + tid]; b1s[tid] = b1[qoff + tid]; }
        __syncthreads();   // qh (and t=0: kh), g1s/b1s visible

        // ---- GEMM1 (1 pass): m[16w+g*4+e][fj*16+l15] = Kh . Qh ----
        const int arow = wid * 16 + l15;
        #pragma unroll
        for (int fj = 0; fj < 4; ++fj) {
            f32x4 mv = (f32x4){0.f, 0.f, 0.f, 0.f};
            const int brow = fj * 16 + l15;
            #pragma unroll
            for (int kk = 0; kk < 8; ++kk) {
                const int c8 = kk * 4 + g;
                const bf16x8 ah = *(const bf16x8*)(kh + ix256(arow, c8, 0));
                const bf16x8 bh = *(const bf16x8*)(qh + ix256(brow, c8, 0));
                mv = MFMA(ah, bh, mv);
            }
            #pragma unroll
            for (int e = 0; e < 4; ++e) {
                const float v = mv[e];
                rsp[e] += v; rssp[e] += v * v;
                const int row = wid * 16 + g * 4 + e;
                const int q = fj * 16 + l15;
                mh[ix64(row, q >> 3, q & 7)] = f2bf(v);
            }
        }
        __syncthreads();   // mh visible; all waves done reading qh

        // ---- stage w = g1*v transposed, bf16-hi: wT[d][q] into qh ----
        #pragma unroll
        for (int q0 = 0; q0 < 4; ++q0) {
            const int qq = wid * 16 + q0 * 4;   // 4-aligned q within tile
            const float g1v0 = g1s[qq], g1v1 = g1s[qq + 1];
            const float g1v2 = g1s[qq + 2], g1v3 = g1s[qq + 3];
            const float b1v0 = b1s[qq], b1v1 = b1s[qq + 1];
            const float b1v2 = b1s[qq + 2], b1v3 = b1s[qq + 3];
            #pragma unroll
            for (int d0 = 0; d0 < 4; ++d0) {
                const int d = d0 * 64 + l;
                const float x0 = vb[(size_t)(qoff + qq + 0) * 256 + d];
                const float x1 = vb[(size_t)(qoff + qq + 1) * 256 + d];
                const float x2 = vb[(size_t)(qoff + qq + 2) * 256 + d];
                const float x3 = vb[(size_t)(qoff + qq + 3) * 256 + d];
                const float w0 = g1v0 * x0, w1 = g1v1 * x1, w2 = g1v2 * x2, w3 = g1v3 * x3;
                c1p[d0] += w0 + w1 + w2 + w3;
                c2p[d0] += b1v0 * x0 + b1v1 * x1 + b1v2 * x2 + b1v3 * x3;
                u16x4 hh = {f2bf(w0), f2bf(w1), f2bf(w2), f2bf(w3)};
                *(u16x4*)(qh + ix64(d, qq >> 3, qq & 7)) = hh;
            }
        }
        __syncthreads();   // wT visible

        // ---- GEMM2 (1 pass): out^T[64w+fi*16+g*4+e][fk*16+l15] += wTh x mh ----
        #pragma unroll
        for (int kk2 = 0; kk2 < 2; ++kk2) {
            const int c8 = kk2 * 4 + g;
            bf16x8 awh[4], bm[4];
            #pragma unroll
            for (int fi = 0; fi < 4; ++fi) {
                const int drow = wid * 64 + fi * 16 + l15;
                awh[fi] = *(const bf16x8*)(qh + ix64(drow, c8, 0));
            }
            #pragma unroll
            for (int fk = 0; fk < 4; ++fk) {
                const int krow = fk * 16 + l15;
                bm[fk] = *(const bf16x8*)(mh + ix64(krow, c8, 0));
            }
            #pragma unroll
            for (int fi = 0; fi < 4; ++fi)
                #pragma unroll
                for (int fk = 0; fk < 4; ++fk)
                    acc[fi][fk] = MFMA(awh[fi], bm[fk], acc[fi][fk]);
        }
    }

    // ================= epilogue =================
    __syncthreads();   // last GEMM2 reads done -> reuse mh, qh as float scratch
    float* redA = (float*)mh;   // 2048 floats
    float* redB = (float*)qh;   // plenty

    #pragma unroll
    for (int d0 = 0; d0 < 4; ++d0) {
        redA[wid * 256 + d0 * 64 + l] = c1p[d0];
        redB[wid * 256 + d0 * 64 + l] = c2p[d0];
    }
    // LN1 stats: reduce rsp/rssp over l15 (q-direction)
    #pragma unroll
    for (int e = 0; e < 4; ++e) {
        float s = rsp[e], ss = rssp[e];
        s += __shfl_xor(s, 1);  ss += __shfl_xor(ss, 1);
        s += __shfl_xor(s, 2);  ss += __shfl_xor(ss, 2);
        s += __shfl_xor(s, 4);  ss += __shfl_xor(ss, 4);
        s += __shfl_xor(s, 8);  ss += __shfl_xor(ss, 8);
        if (l15 == 0) {
            const int k = wid * 16 + g * 4 + e;
            const float mu = s * (1.f / 1024.f);
            const float var = ss * (1.f / 1024.f) - mu * mu;
            muA[k] = mu;
            invA[k] = rsqrtf(var + 1e-3f);
        }
    }
    __syncthreads();
    {
        const float c1s = redA[tid] + redA[256 + tid] + redA[512 + tid] + redA[768 + tid];
        const float c2s = redB[tid] + redB[256 + tid] + redB[512 + tid] + redB[768 + tid];
        c1f[tid] = c1s;
        c2f[tid] = c2s;
    }
    __syncthreads();

    // LN1-fixup in registers + LN2 partial stats
    float s2p[4] = {0.f, 0.f, 0.f, 0.f}, ss2p[4] = {0.f, 0.f, 0.f, 0.f};
    #pragma unroll
    for (int fi = 0; fi < 4; ++fi) {
        const int dbase = wid * 64 + fi * 16 + g * 4;
        const float4 c1v = *(const float4*)(c1f + dbase);
        const float4 c2v = *(const float4*)(c2f + dbase);
        #pragma unroll
        for (int fk = 0; fk < 4; ++fk) {
            const int k = fk * 16 + l15;
            const float mu = muA[k], inv = invA[k];
            float pre;
            pre = inv * (acc[fi][fk][0] - mu * c1v.x) + c2v.x; acc[fi][fk][0] = pre;
            s2p[fk] += pre; ss2p[fk] += pre * pre;
            pre = inv * (acc[fi][fk][1] - mu * c1v.y) + c2v.y; acc[fi][fk][1] = pre;
            s2p[fk] += pre; ss2p[fk] += pre * pre;
            pre = inv * (acc[fi][fk][2] - mu * c1v.z) + c2v.z; acc[fi][fk][2] = pre;
            s2p[fk] += pre; ss2p[fk] += pre * pre;
            pre = inv * (acc[fi][fk][3] - mu * c1v.w) + c2v.w; acc[fi][fk][3] = pre;
            s2p[fk] += pre; ss2p[fk] += pre * pre;
        }
    }
    __syncthreads();   // redA/redB free for LN2 reuse
    #pragma unroll
    for (int fk = 0; fk < 4; ++fk) {
        float s = s2p[fk], ss = ss2p[fk];
        s += __shfl_xor(s, 16); ss += __shfl_xor(ss, 16);
        s += __shfl_xor(s, 32); ss += __shfl_xor(ss, 32);
        if (g == 0) {   // l < 16
            redA[wid * 64 + fk * 16 + l15] = s;
            redB[wid * 64 + fk * 16 + l15] = ss;
        }
    }
    __syncthreads();
    if (tid < 64) {
        const float s  = redA[tid] + redA[64 + tid] + redA[128 + tid] + redA[192 + tid];
        const float ss = redB[tid] + redB[64 + tid] + redB[128 + tid] + redB[192 + tid];
        const float mu = s * (1.f / 256.f);
        const float var = ss * (1.f / 256.f) - mu * mu;
        mu2[tid] = mu;
        inv2[tid] = rsqrtf(var + 1e-3f);
    }
    __syncthreads();

    // final LN2 apply + store (out^T frags -> row-major out)
    #pragma unroll
    for (int fi = 0; fi < 4; ++fi) {
        const int dbase = wid * 64 + fi * 16 + g * 4;
        const float4 gv = *(const float4*)(g2 + dbase);
        const float4 bv = *(const float4*)(b2 + dbase);
        #pragma unroll
        for (int fk = 0; fk < 4; ++fk) {
            const int k = fk * 16 + l15;
            const float mu = mu2[k], inv = inv2[k];
            float4 o;
            o.x = (acc[fi][fk][0] - mu) * inv * gv.x + bv.x;
            o.y = (acc[fi][fk][1] - mu) * inv * gv.y + bv.y;
            o.z = (acc[fi][fk][2] - mu) * inv * gv.z + bv.z;
            o.w = (acc[fi][fk][3] - mu) * inv * gv.w + bv.w;
            *(float4*)(out + (size_t)(b * 1024 + kt * 64 + k) * 256 + dbase) = o;
        }
    }
}

extern "C" void kernel_launch(void* const* d_in, const int* in_sizes, int n_in,
                              void* d_out, int out_size, void* d_ws, size_t ws_size,
                              hipStream_t stream) {
    const float* kin = (const float*)d_in[0];
    const float* qin = (const float*)d_in[1];
    const float* vin = (const float*)d_in[2];
    const float* g1  = (const float*)d_in[3];
    const float* b1  = (const float*)d_in[4];
    const float* g2  = (const float*)d_in[5];
    const float* b2  = (const float*)d_in[6];
    float* out = (float*)d_out;

    hipLaunchKernelGGL(capsule_mfma4_kernel, dim3(512), dim3(256), 0, stream,
                       kin, qin, vin, g1, b1, g2, b2, out);
}

// Round 10
// 573.929 us; speedup vs baseline: 1.2859x; 1.1678x over previous
//
#include <hip/hip_runtime.h>

// CapsuleMappingTiny on MFMA, v5: skeleton attack.
// v4 post-mortem: traffic minimal (84MB), zero spill, but all pipes idle
// (Mfma 2.3%, VALU 10%, occ 12%) -> serial stage/barrier skeleton with
// exposed latencies dominates. v5: 8 waves/block (512thr) so per-wave
// staging halves and acc=32 AGPR; __launch_bounds__(512,4) caps regs at 128
// -> 2 blocks/CU (4 waves/SIMD); q(t+1) and v(t) register-prefetched and
// preprocessed during GEMM1 (VALU overlaps MFMA, loads hide under compute).
// Same math as v4 (absmax 0.03125).

typedef __attribute__((ext_vector_type(8))) short bf16x8;
typedef __attribute__((ext_vector_type(4))) float f32x4;
typedef __attribute__((ext_vector_type(4))) unsigned short u16x4;
typedef unsigned short u16;

#define MFMA(a, b, c) __builtin_amdgcn_mfma_f32_16x16x32_bf16((a), (b), (c), 0, 0, 0)

__device__ __forceinline__ u16 f2bf(float x) {
    union { float f; unsigned u; } v; v.f = x;
    unsigned r = v.u + 0x7fffu + ((v.u >> 16) & 1u);
    return (u16)(r >> 16);
}
// swizzled ushort index; c8 = 16B chunk index, c0 = ushort within chunk
__device__ __forceinline__ int ix256(int r, int c8, int c0) {
    return r * 256 + (((c8) ^ (r & 7)) << 3) + c0;
}
__device__ __forceinline__ int ix64(int r, int c8, int c0) {
    return r * 64 + (((c8) ^ (r & 7)) << 3) + c0;
}

__global__ __launch_bounds__(512, 4)
void capsule_mfma5_kernel(const float* __restrict__ kin,
                          const float* __restrict__ qin,
                          const float* __restrict__ vin,
                          const float* __restrict__ g1,
                          const float* __restrict__ b1,
                          const float* __restrict__ g2,
                          const float* __restrict__ b2,
                          float* __restrict__ out)
{
    // 77,312 B -> 2 blocks/CU (16 waves/CU)
    __shared__ __align__(16) u16 kh[64 * 256];   // 32 KB  kn hi (persistent)
    __shared__ __align__(16) u16 qh[64 * 256];   // 32 KB  qn hi / wT hi [256][64]
    __shared__ __align__(16) u16 mh[64 * 64];    // 8 KB   m hi / epilogue scratch
    __shared__ float g1s[64], b1s[64];
    __shared__ float c1f[256], c2f[256];
    __shared__ float muA[64], invA[64], mu2[64], inv2[64];

    const int tid = threadIdx.x;
    const int wid = tid >> 6;         // wave 0..7
    const int l   = tid & 63;
    const int g   = l >> 4;
    const int l15 = l & 15;
    // XCD swizzle (validated in v4: FETCH 783->49MB)
    const int lb  = ((blockIdx.x & 7) << 6) | (blockIdx.x >> 3);
    const int b   = lb >> 4;
    const int kt  = lb & 15;

    const float* kb = kin + (size_t)(b * 1024 + kt * 64) * 256;
    const float* qb = qin + (size_t)b * 1024 * 256;
    const float* vb = vin + (size_t)b * 1024 * 256;

    // ---- prologue: stage + normalize K tile (8 rows/wave) ----
    #pragma unroll
    for (int i = 0; i < 8; ++i) {
        const int r = i * 8 + wid;
        float4 x = *(const float4*)(kb + r * 256 + l * 4);
        float ssq = x.x * x.x + x.y * x.y + x.z * x.z + x.w * x.w;
        #pragma unroll
        for (int s = 1; s < 64; s <<= 1) ssq += __shfl_xor(ssq, s);
        const float sc = rsqrtf(fmaxf(ssq, 1e-12f));
        u16x4 hh = {f2bf(sc * x.x), f2bf(sc * x.y), f2bf(sc * x.z), f2bf(sc * x.w)};
        *(u16x4*)(kh + ix256(r, l >> 1, (l & 1) * 4)) = hh;
    }

    // q(0) prefetch into registers (8 float4 = 32 VGPR)
    float4 qpre[8];
    #pragma unroll
    for (int i = 0; i < 8; ++i)
        qpre[i] = *(const float4*)(qb + (size_t)(i * 8 + wid) * 256 + l * 4);

    // persistent state
    f32x4 acc[2][4];                  // out^T frags [fi d][fk k], 32 AGPR
    #pragma unroll
    for (int i = 0; i < 2; ++i)
        #pragma unroll
        for (int j = 0; j < 4; ++j) acc[i][j] = (f32x4){0.f, 0.f, 0.f, 0.f};
    float rsp[4]  = {0.f, 0.f, 0.f, 0.f};
    float rssp[4] = {0.f, 0.f, 0.f, 0.f};
    float c1p[4]  = {0.f, 0.f, 0.f, 0.f};   // per-lane d = d0*64 + l
    float c2p[4]  = {0.f, 0.f, 0.f, 0.f};

    const int f0   = (wid >> 2) * 2;          // GEMM1 fj base for this wave
    const int arow = (wid & 3) * 16 + l15;    // GEMM1 A row

    #pragma unroll 1
    for (int qt = 0; qt < 16; ++qt) {
        const int qoff = qt * 64;
        __syncthreads();   // GEMM2(t-1) done with qh/mh; (t=0: kh staged)

        // ---- stage q(t) from prefetch regs (normalize + convert) ----
        #pragma unroll
        for (int i = 0; i < 8; ++i) {
            const int r = i * 8 + wid;
            const float4 x = qpre[i];
            float ssq = x.x * x.x + x.y * x.y + x.z * x.z + x.w * x.w;
            #pragma unroll
            for (int s = 1; s < 64; s <<= 1) ssq += __shfl_xor(ssq, s);
            const float sc = rsqrtf(fmaxf(ssq, 1e-12f));
            u16x4 hh = {f2bf(sc * x.x), f2bf(sc * x.y), f2bf(sc * x.z), f2bf(sc * x.w)};
            *(u16x4*)(qh + ix256(r, l >> 1, (l & 1) * 4)) = hh;
        }
        if (tid < 64) { g1s[tid] = g1[qoff + tid]; b1s[tid] = b1[qoff + tid]; }
        __syncthreads();   // qh, g1s/b1s ready

        // ---- overlap region: q(t+1) prefetch + v(t) load/preprocess + GEMM1 ----
        if (qt < 15) {
            #pragma unroll
            for (int i = 0; i < 8; ++i)
                qpre[i] = *(const float4*)(qb + (size_t)(qoff + 64 + i * 8 + wid) * 256 + l * 4);
        }

        // v(t): load, fold g1/b1 (c1/c2 FMA), pack w=g1*v to bf16 (16 VGPR)
        u16x4 wpre[2][4];
        #pragma unroll
        for (int q0 = 0; q0 < 2; ++q0) {
            const int qq = wid * 8 + q0 * 4;
            const float g10 = g1s[qq], g11 = g1s[qq + 1], g12 = g1s[qq + 2], g13 = g1s[qq + 3];
            const float b10 = b1s[qq], b11 = b1s[qq + 1], b12 = b1s[qq + 2], b13 = b1s[qq + 3];
            #pragma unroll
            for (int d0 = 0; d0 < 4; ++d0) {
                const int d = d0 * 64 + l;
                const float x0 = vb[(size_t)(qoff + qq + 0) * 256 + d];
                const float x1 = vb[(size_t)(qoff + qq + 1) * 256 + d];
                const float x2 = vb[(size_t)(qoff + qq + 2) * 256 + d];
                const float x3 = vb[(size_t)(qoff + qq + 3) * 256 + d];
                const float w0 = g10 * x0, w1 = g11 * x1, w2 = g12 * x2, w3 = g13 * x3;
                c1p[d0] += w0 + w1 + w2 + w3;
                c2p[d0] += b10 * x0 + b11 * x1 + b12 * x2 + b13 * x3;
                wpre[q0][d0] = (u16x4){f2bf(w0), f2bf(w1), f2bf(w2), f2bf(w3)};
            }
        }

        // GEMM1: m[(wid&3)*16+g*4+e][(f0+fj2)*16+l15], 16 MFMA/wave
        f32x4 macc[2];
        macc[0] = (f32x4){0.f, 0.f, 0.f, 0.f};
        macc[1] = (f32x4){0.f, 0.f, 0.f, 0.f};
        #pragma unroll
        for (int kk = 0; kk < 8; ++kk) {
            const int c8 = kk * 4 + g;
            const bf16x8 ah = *(const bf16x8*)(kh + ix256(arow, c8, 0));
            #pragma unroll
            for (int fj2 = 0; fj2 < 2; ++fj2) {
                const int brow = (f0 + fj2) * 16 + l15;
                const bf16x8 bh = *(const bf16x8*)(qh + ix256(brow, c8, 0));
                macc[fj2] = MFMA(ah, bh, macc[fj2]);
            }
        }
        // LN1 raw stats + m -> bf16 into mh
        #pragma unroll
        for (int fj2 = 0; fj2 < 2; ++fj2) {
            #pragma unroll
            for (int e = 0; e < 4; ++e) {
                const float v = macc[fj2][e];
                rsp[e] += v; rssp[e] += v * v;
                const int row = (wid & 3) * 16 + g * 4 + e;
                const int q = (f0 + fj2) * 16 + l15;
                mh[ix64(row, q >> 3, q & 7)] = f2bf(v);
            }
        }
        __syncthreads();   // mh ready; all waves done reading qh

        // ---- wT write (just ds_writes; work was done during GEMM1) ----
        #pragma unroll
        for (int q0 = 0; q0 < 2; ++q0) {
            const int qq = wid * 8 + q0 * 4;
            #pragma unroll
            for (int d0 = 0; d0 < 4; ++d0) {
                const int d = d0 * 64 + l;
                *(u16x4*)(qh + ix64(d, qq >> 3, qq & 7)) = wpre[q0][d0];
            }
        }
        __syncthreads();   // wT ready

        // ---- GEMM2: out^T[wid*32+fi*16+g*4+e][fk*16+l15], 16 MFMA/wave ----
        #pragma unroll
        for (int kk2 = 0; kk2 < 2; ++kk2) {
            const int c8 = kk2 * 4 + g;
            bf16x8 aw[2], bm[4];
            #pragma unroll
            for (int fi = 0; fi < 2; ++fi)
                aw[fi] = *(const bf16x8*)(qh + ix64(wid * 32 + fi * 16 + l15, c8, 0));
            #pragma unroll
            for (int fk = 0; fk < 4; ++fk)
                bm[fk] = *(const bf16x8*)(mh + ix64(fk * 16 + l15, c8, 0));
            #pragma unroll
            for (int fi = 0; fi < 2; ++fi)
                #pragma unroll
                for (int fk = 0; fk < 4; ++fk)
                    acc[fi][fk] = MFMA(aw[fi], bm[fk], acc[fi][fk]);
        }
    }

    // ================= epilogue =================
    __syncthreads();   // all LDS reusable
    float* redA = (float*)mh;   // 2048 f: c1 partials, later LN2 s
    float* redB = (float*)qh;   // 8192 f: c2 partials, later LN2 ss
    float* redS = (float*)kh;   // LN1 stats: s[0..127], ss[128..255]

    #pragma unroll
    for (int d0 = 0; d0 < 4; ++d0) {
        redA[wid * 256 + d0 * 64 + l] = c1p[d0];
        redB[wid * 256 + d0 * 64 + l] = c2p[d0];
    }
    #pragma unroll
    for (int e = 0; e < 4; ++e) {
        float s = rsp[e], ss = rssp[e];
        s += __shfl_xor(s, 1);  ss += __shfl_xor(ss, 1);
        s += __shfl_xor(s, 2);  ss += __shfl_xor(ss, 2);
        s += __shfl_xor(s, 4);  ss += __shfl_xor(ss, 4);
        s += __shfl_xor(s, 8);  ss += __shfl_xor(ss, 8);
        if (l15 == 0) {
            const int k = (wid & 3) * 16 + g * 4 + e;
            const int hw = wid >> 2;
            redS[hw * 64 + k] = s;
            redS[128 + hw * 64 + k] = ss;
        }
    }
    __syncthreads();
    if (tid < 64) {
        const float s  = redS[tid] + redS[64 + tid];
        const float ss = redS[128 + tid] + redS[192 + tid];
        const float mu = s * (1.f / 1024.f);
        const float var = ss * (1.f / 1024.f) - mu * mu;
        muA[tid] = mu;
        invA[tid] = rsqrtf(var + 1e-3f);
    }
    if (tid < 256) {
        float c1s = 0.f, c2s = 0.f;
        #pragma unroll
        for (int w = 0; w < 8; ++w) {
            c1s += redA[w * 256 + tid];
            c2s += redB[w * 256 + tid];
        }
        c1f[tid] = c1s;
        c2f[tid] = c2s;
    }
    __syncthreads();

    // LN1-fixup in registers + LN2 partial stats
    float s2p[4] = {0.f, 0.f, 0.f, 0.f}, ss2p[4] = {0.f, 0.f, 0.f, 0.f};
    #pragma unroll
    for (int fi = 0; fi < 2; ++fi) {
        const int dbase = wid * 32 + fi * 16 + g * 4;
        const float4 c1v = *(const float4*)(c1f + dbase);
        const float4 c2v = *(const float4*)(c2f + dbase);
        #pragma unroll
        for (int fk = 0; fk < 4; ++fk) {
            const int k = fk * 16 + l15;
            const float mu = muA[k], inv = invA[k];
            float pre;
            pre = inv * (acc[fi][fk][0] - mu * c1v.x) + c2v.x; acc[fi][fk][0] = pre;
            s2p[fk] += pre; ss2p[fk] += pre * pre;
            pre = inv * (acc[fi][fk][1] - mu * c1v.y) + c2v.y; acc[fi][fk][1] = pre;
            s2p[fk] += pre; ss2p[fk] += pre * pre;
            pre = inv * (acc[fi][fk][2] - mu * c1v.z) + c2v.z; acc[fi][fk][2] = pre;
            s2p[fk] += pre; ss2p[fk] += pre * pre;
            pre = inv * (acc[fi][fk][3] - mu * c1v.w) + c2v.w; acc[fi][fk][3] = pre;
            s2p[fk] += pre; ss2p[fk] += pre * pre;
        }
    }
    __syncthreads();   // redA/redB free for LN2 reuse
    #pragma unroll
    for (int fk = 0; fk < 4; ++fk) {
        float s = s2p[fk], ss = ss2p[fk];
        s += __shfl_xor(s, 16); ss += __shfl_xor(ss, 16);
        s += __shfl_xor(s, 32); ss += __shfl_xor(ss, 32);
        if (g == 0) {
            redA[wid * 64 + fk * 16 + l15] = s;
            redB[wid * 64 + fk * 16 + l15] = ss;
        }
    }
    __syncthreads();
    if (tid < 64) {
        float s = 0.f, ss = 0.f;
        #pragma unroll
        for (int w = 0; w < 8; ++w) {
            s += redA[w * 64 + tid];
            ss += redB[w * 64 + tid];
        }
        const float mu = s * (1.f / 256.f);
        const float var = ss * (1.f / 256.f) - mu * mu;
        mu2[tid] = mu;
        inv2[tid] = rsqrtf(var + 1e-3f);
    }
    __syncthreads();

    // final LN2 apply + store
    #pragma unroll
    for (int fi = 0; fi < 2; ++fi) {
        const int dbase = wid * 32 + fi * 16 + g * 4;
        const float4 gv = *(const float4*)(g2 + dbase);
        const float4 bv = *(const float4*)(b2 + dbase);
        #pragma unroll
        for (int fk = 0; fk < 4; ++fk) {
            const int k = fk * 16 + l15;
            const float mu = mu2[k], inv = inv2[k];
            float4 o;
            o.x = (acc[fi][fk][0] - mu) * inv * gv.x + bv.x;
            o.y = (acc[fi][fk][1] - mu) * inv * gv.y + bv.y;
            o.z = (acc[fi][fk][2] - mu) * inv * gv.z + bv.z;
            o.w = (acc[fi][fk][3] - mu) * inv * gv.w + bv.w;
            *(float4*)(out + (size_t)(b * 1024 + kt * 64 + k) * 256 + dbase) = o;
        }
    }
}

extern "C" void kernel_launch(void* const* d_in, const int* in_sizes, int n_in,
                              void* d_out, int out_size, void* d_ws, size_t ws_size,
                              hipStream_t stream) {
    const float* kin = (const float*)d_in[0];
    const float* qin = (const float*)d_in[1];
    const float* vin = (const float*)d_in[2];
    const float* g1  = (const float*)d_in[3];
    const float* b1  = (const float*)d_in[4];
    const float* g2  = (const float*)d_in[5];
    const float* b2  = (const float*)d_in[6];
    float* out = (float*)d_out;

    hipLaunchKernelGGL(capsule_mfma5_kernel, dim3(512), dim3(512), 0, stream,
                       kin, qin, vin, g1, b1, g2, b2, out);
}

// Round 11
// 396.792 us; speedup vs baseline: 1.8600x; 1.4464x over previous
//
#include <hip/hip_runtime.h>

// CapsuleMappingTiny on MFMA, v6: v5 minus the spiller.
// v5 post-mortem: occ 45.9% (good, 2x8-wave blocks/CU) but compiler pinned
// VGPR=64 (8 waves/SIMD target, impossible under 77KB LDS) and spilled the
// persistent qpre[8] register prefetch -> 1.5GB scratch traffic = the new
// limiter (3.2TB/s observed). v6: drop qpre (TLP covers q-load latency at
// 4 waves/SIMD x 2 blocks), keep the cheap wpre overlap (8 VGPR),
// __launch_bounds__(512,2) to raise the cap. Same math (absmax 0.03125).

typedef __attribute__((ext_vector_type(8))) short bf16x8;
typedef __attribute__((ext_vector_type(4))) float f32x4;
typedef __attribute__((ext_vector_type(4))) unsigned short u16x4;
typedef unsigned short u16;

#define MFMA(a, b, c) __builtin_amdgcn_mfma_f32_16x16x32_bf16((a), (b), (c), 0, 0, 0)

__device__ __forceinline__ u16 f2bf(float x) {
    union { float f; unsigned u; } v; v.f = x;
    unsigned r = v.u + 0x7fffu + ((v.u >> 16) & 1u);
    return (u16)(r >> 16);
}
// swizzled ushort index; c8 = 16B chunk index, c0 = ushort within chunk
__device__ __forceinline__ int ix256(int r, int c8, int c0) {
    return r * 256 + (((c8) ^ (r & 7)) << 3) + c0;
}
__device__ __forceinline__ int ix64(int r, int c8, int c0) {
    return r * 64 + (((c8) ^ (r & 7)) << 3) + c0;
}

__global__ __launch_bounds__(512, 2)
void capsule_mfma6_kernel(const float* __restrict__ kin,
                          const float* __restrict__ qin,
                          const float* __restrict__ vin,
                          const float* __restrict__ g1,
                          const float* __restrict__ b1,
                          const float* __restrict__ g2,
                          const float* __restrict__ b2,
                          float* __restrict__ out)
{
    // 77,312 B -> 2 blocks/CU (16 waves/CU)
    __shared__ __align__(16) u16 kh[64 * 256];   // 32 KB  kn hi (persistent)
    __shared__ __align__(16) u16 qh[64 * 256];   // 32 KB  qn hi / wT hi [256][64]
    __shared__ __align__(16) u16 mh[64 * 64];    // 8 KB   m hi / epilogue scratch
    __shared__ float g1s[64], b1s[64];
    __shared__ float c1f[256], c2f[256];
    __shared__ float muA[64], invA[64], mu2[64], inv2[64];

    const int tid = threadIdx.x;
    const int wid = tid >> 6;         // wave 0..7
    const int l   = tid & 63;
    const int g   = l >> 4;
    const int l15 = l & 15;
    // XCD swizzle (validated in v4: FETCH 783->49MB)
    const int lb  = ((blockIdx.x & 7) << 6) | (blockIdx.x >> 3);
    const int b   = lb >> 4;
    const int kt  = lb & 15;

    const float* kb = kin + (size_t)(b * 1024 + kt * 64) * 256;
    const float* qb = qin + (size_t)b * 1024 * 256;
    const float* vb = vin + (size_t)b * 1024 * 256;

    // ---- prologue: stage + normalize K tile (8 rows/wave) ----
    #pragma unroll
    for (int i = 0; i < 8; ++i) {
        const int r = i * 8 + wid;
        float4 x = *(const float4*)(kb + r * 256 + l * 4);
        float ssq = x.x * x.x + x.y * x.y + x.z * x.z + x.w * x.w;
        #pragma unroll
        for (int s = 1; s < 64; s <<= 1) ssq += __shfl_xor(ssq, s);
        const float sc = rsqrtf(fmaxf(ssq, 1e-12f));
        u16x4 hh = {f2bf(sc * x.x), f2bf(sc * x.y), f2bf(sc * x.z), f2bf(sc * x.w)};
        *(u16x4*)(kh + ix256(r, l >> 1, (l & 1) * 4)) = hh;
    }

    // persistent state
    f32x4 acc[2][4];                  // out^T frags [fi d][fk k], 32 AGPR
    #pragma unroll
    for (int i = 0; i < 2; ++i)
        #pragma unroll
        for (int j = 0; j < 4; ++j) acc[i][j] = (f32x4){0.f, 0.f, 0.f, 0.f};
    float rsp[4]  = {0.f, 0.f, 0.f, 0.f};
    float rssp[4] = {0.f, 0.f, 0.f, 0.f};
    float c1p[4]  = {0.f, 0.f, 0.f, 0.f};   // per-lane d = d0*64 + l
    float c2p[4]  = {0.f, 0.f, 0.f, 0.f};

    const int f0   = (wid >> 2) * 2;          // GEMM1 fj base for this wave
    const int arow = (wid & 3) * 16 + l15;    // GEMM1 A row

    #pragma unroll 1
    for (int qt = 0; qt < 16; ++qt) {
        const int qoff = qt * 64;
        __syncthreads();   // GEMM2(t-1) done with qh/mh; (t=0: kh staged)

        // ---- stage + normalize q(t) (direct loads; TLP hides latency) ----
        #pragma unroll
        for (int i = 0; i < 8; ++i) {
            const int r = i * 8 + wid;
            float4 x = *(const float4*)(qb + (size_t)(qoff + r) * 256 + l * 4);
            float ssq = x.x * x.x + x.y * x.y + x.z * x.z + x.w * x.w;
            #pragma unroll
            for (int s = 1; s < 64; s <<= 1) ssq += __shfl_xor(ssq, s);
            const float sc = rsqrtf(fmaxf(ssq, 1e-12f));
            u16x4 hh = {f2bf(sc * x.x), f2bf(sc * x.y), f2bf(sc * x.z), f2bf(sc * x.w)};
            *(u16x4*)(qh + ix256(r, l >> 1, (l & 1) * 4)) = hh;
        }
        if (tid < 64) { g1s[tid] = g1[qoff + tid]; b1s[tid] = b1[qoff + tid]; }
        __syncthreads();   // qh, g1s/b1s ready

        // ---- overlap: v(t) load + preprocess (c1/c2 FMA, bf16 pack) + GEMM1 ----
        u16x4 wpre[2][4];
        #pragma unroll
        for (int q0 = 0; q0 < 2; ++q0) {
            const int qq = wid * 8 + q0 * 4;
            const float g10 = g1s[qq], g11 = g1s[qq + 1], g12 = g1s[qq + 2], g13 = g1s[qq + 3];
            const float b10 = b1s[qq], b11 = b1s[qq + 1], b12 = b1s[qq + 2], b13 = b1s[qq + 3];
            #pragma unroll
            for (int d0 = 0; d0 < 4; ++d0) {
                const int d = d0 * 64 + l;
                const float x0 = vb[(size_t)(qoff + qq + 0) * 256 + d];
                const float x1 = vb[(size_t)(qoff + qq + 1) * 256 + d];
                const float x2 = vb[(size_t)(qoff + qq + 2) * 256 + d];
                const float x3 = vb[(size_t)(qoff + qq + 3) * 256 + d];
                const float w0 = g10 * x0, w1 = g11 * x1, w2 = g12 * x2, w3 = g13 * x3;
                c1p[d0] += w0 + w1 + w2 + w3;
                c2p[d0] += b10 * x0 + b11 * x1 + b12 * x2 + b13 * x3;
                wpre[q0][d0] = (u16x4){f2bf(w0), f2bf(w1), f2bf(w2), f2bf(w3)};
            }
        }

        // GEMM1: m[(wid&3)*16+g*4+e][(f0+fj2)*16+l15], 16 MFMA/wave
        f32x4 macc[2];
        macc[0] = (f32x4){0.f, 0.f, 0.f, 0.f};
        macc[1] = (f32x4){0.f, 0.f, 0.f, 0.f};
        #pragma unroll
        for (int kk = 0; kk < 8; ++kk) {
            const int c8 = kk * 4 + g;
            const bf16x8 ah = *(const bf16x8*)(kh + ix256(arow, c8, 0));
            #pragma unroll
            for (int fj2 = 0; fj2 < 2; ++fj2) {
                const int brow = (f0 + fj2) * 16 + l15;
                const bf16x8 bh = *(const bf16x8*)(qh + ix256(brow, c8, 0));
                macc[fj2] = MFMA(ah, bh, macc[fj2]);
            }
        }
        // LN1 raw stats + m -> bf16 into mh
        #pragma unroll
        for (int fj2 = 0; fj2 < 2; ++fj2) {
            #pragma unroll
            for (int e = 0; e < 4; ++e) {
                const float v = macc[fj2][e];
                rsp[e] += v; rssp[e] += v * v;
                const int row = (wid & 3) * 16 + g * 4 + e;
                const int q = (f0 + fj2) * 16 + l15;
                mh[ix64(row, q >> 3, q & 7)] = f2bf(v);
            }
        }
        __syncthreads();   // mh ready; all waves done reading qh

        // ---- wT write (just ds_writes; work was done during GEMM1) ----
        #pragma unroll
        for (int q0 = 0; q0 < 2; ++q0) {
            const int qq = wid * 8 + q0 * 4;
            #pragma unroll
            for (int d0 = 0; d0 < 4; ++d0) {
                const int d = d0 * 64 + l;
                *(u16x4*)(qh + ix64(d, qq >> 3, qq & 7)) = wpre[q0][d0];
            }
        }
        __syncthreads();   // wT ready

        // ---- GEMM2: out^T[wid*32+fi*16+g*4+e][fk*16+l15], 16 MFMA/wave ----
        #pragma unroll
        for (int kk2 = 0; kk2 < 2; ++kk2) {
            const int c8 = kk2 * 4 + g;
            bf16x8 aw[2], bm[4];
            #pragma unroll
            for (int fi = 0; fi < 2; ++fi)
                aw[fi] = *(const bf16x8*)(qh + ix64(wid * 32 + fi * 16 + l15, c8, 0));
            #pragma unroll
            for (int fk = 0; fk < 4; ++fk)
                bm[fk] = *(const bf16x8*)(mh + ix64(fk * 16 + l15, c8, 0));
            #pragma unroll
            for (int fi = 0; fi < 2; ++fi)
                #pragma unroll
                for (int fk = 0; fk < 4; ++fk)
                    acc[fi][fk] = MFMA(aw[fi], bm[fk], acc[fi][fk]);
        }
    }

    // ================= epilogue =================
    __syncthreads();   // all LDS reusable
    float* redA = (float*)mh;   // 2048 f: c1 partials, later LN2 s
    float* redB = (float*)qh;   // 8192 f: c2 partials, later LN2 ss
    float* redS = (float*)kh;   // LN1 stats: s[0..127], ss[128..255]

    #pragma unroll
    for (int d0 = 0; d0 < 4; ++d0) {
        redA[wid * 256 + d0 * 64 + l] = c1p[d0];
        redB[wid * 256 + d0 * 64 + l] = c2p[d0];
    }
    #pragma unroll
    for (int e = 0; e < 4; ++e) {
        float s = rsp[e], ss = rssp[e];
        s += __shfl_xor(s, 1);  ss += __shfl_xor(ss, 1);
        s += __shfl_xor(s, 2);  ss += __shfl_xor(ss, 2);
        s += __shfl_xor(s, 4);  ss += __shfl_xor(ss, 4);
        s += __shfl_xor(s, 8);  ss += __shfl_xor(ss, 8);
        if (l15 == 0) {
            const int k = (wid & 3) * 16 + g * 4 + e;
            const int hw = wid >> 2;
            redS[hw * 64 + k] = s;
            redS[128 + hw * 64 + k] = ss;
        }
    }
    __syncthreads();
    if (tid < 64) {
        const float s  = redS[tid] + redS[64 + tid];
        const float ss = redS[128 + tid] + redS[192 + tid];
        const float mu = s * (1.f / 1024.f);
        const float var = ss * (1.f / 1024.f) - mu * mu;
        muA[tid] = mu;
        invA[tid] = rsqrtf(var + 1e-3f);
    }
    if (tid < 256) {
        float c1s = 0.f, c2s = 0.f;
        #pragma unroll
        for (int w = 0; w < 8; ++w) {
            c1s += redA[w * 256 + tid];
            c2s += redB[w * 256 + tid];
        }
        c1f[tid] = c1s;
        c2f[tid] = c2s;
    }
    __syncthreads();

    // LN1-fixup in registers + LN2 partial stats
    float s2p[4] = {0.f, 0.f, 0.f, 0.f}, ss2p[4] = {0.f, 0.f, 0.f, 0.f};
    #pragma unroll
    for (int fi = 0; fi < 2; ++fi) {
        const int dbase = wid * 32 + fi * 16 + g * 4;
        const float4 c1v = *(const float4*)(c1f + dbase);
        const float4 c2v = *(const float4*)(c2f + dbase);
        #pragma unroll
        for (int fk = 0; fk < 4; ++fk) {
            const int k = fk * 16 + l15;
            const float mu = muA[k], inv = invA[k];
            float pre;
            pre = inv * (acc[fi][fk][0] - mu * c1v.x) + c2v.x; acc[fi][fk][0] = pre;
            s2p[fk] += pre; ss2p[fk] += pre * pre;
            pre = inv * (acc[fi][fk][1] - mu * c1v.y) + c2v.y; acc[fi][fk][1] = pre;
            s2p[fk] += pre; ss2p[fk] += pre * pre;
            pre = inv * (acc[fi][fk][2] - mu * c1v.z) + c2v.z; acc[fi][fk][2] = pre;
            s2p[fk] += pre; ss2p[fk] += pre * pre;
            pre = inv * (acc[fi][fk][3] - mu * c1v.w) + c2v.w; acc[fi][fk][3] = pre;
            s2p[fk] += pre; ss2p[fk] += pre * pre;
        }
    }
    __syncthreads();   // redA/redB free for LN2 reuse
    #pragma unroll
    for (int fk = 0; fk < 4; ++fk) {
        float s = s2p[fk], ss = ss2p[fk];
        s += __shfl_xor(s, 16); ss += __shfl_xor(ss, 16);
        s += __shfl_xor(s, 32); ss += __shfl_xor(ss, 32);
        if (g == 0) {
            redA[wid * 64 + fk * 16 + l15] = s;
            redB[wid * 64 + fk * 16 + l15] = ss;
        }
    }
    __syncthreads();
    if (tid < 64) {
        float s = 0.f, ss = 0.f;
        #pragma unroll
        for (int w = 0; w < 8; ++w) {
            s += redA[w * 64 + tid];
            ss += redB[w * 64 + tid];
        }
        const float mu = s * (1.f / 256.f);
        const float var = ss * (1.f / 256.f) - mu * mu;
        mu2[tid] = mu;
        inv2[tid] = rsqrtf(var + 1e-3f);
    }
    __syncthreads();

    // final LN2 apply + store
    #pragma unroll
    for (int fi = 0; fi < 2; ++fi) {
        const int dbase = wid * 32 + fi * 16 + g * 4;
        const float4 gv = *(const float4*)(g2 + dbase);
        const float4 bv = *(const float4*)(b2 + dbase);
        #pragma unroll
        for (int fk = 0; fk < 4; ++fk) {
            const int k = fk * 16 + l15;
            const float mu = mu2[k], inv = inv2[k];
            float4 o;
            o.x = (acc[fi][fk][0] - mu) * inv * gv.x + bv.x;
            o.y = (acc[fi][fk][1] - mu) * inv * gv.y + bv.y;
            o.z = (acc[fi][fk][2] - mu) * inv * gv.z + bv.z;
            o.w = (acc[fi][fk][3] - mu) * inv * gv.w + bv.w;
            *(float4*)(out + (size_t)(b * 1024 + kt * 64 + k) * 256 + dbase) = o;
        }
    }
}

extern "C" void kernel_launch(void* const* d_in, const int* in_sizes, int n_in,
                              void* d_out, int out_size, void* d_ws, size_t ws_size,
                              hipStream_t stream) {
    const float* kin = (const float*)d_in[0];
    const float* qin = (const float*)d_in[1];
    const float* vin = (const float*)d_in[2];
    const float* g1  = (const float*)d_in[3];
    const float* b1  = (const float*)d_in[4];
    const float* g2  = (const float*)d_in[5];
    const float* b2  = (const float*)d_in[6];
    float* out = (float*)d_out;

    hipLaunchKernelGGL(capsule_mfma6_kernel, dim3(512), dim3(512), 0, stream,
                       kin, qin, vin, g1, b1, g2, b2, out);
}